// Round 3
// baseline (411.361 us; speedup 1.0000x reference)
//
#include <hip/hip_runtime.h>
#include <hip/hip_cooperative_groups.h>

namespace cg = cooperative_groups;

#define NN 32
#define CC 256
#define HH 56
#define WW 56
#define HWSZ 3136            // 56*56
#define QPP 784              // float4 quads per spatial plane
#define NQ 25088             // quads over N*HW = 32*784
#define NHW 100352           // 32*3136
#define TOT4 6422528         // 32*256*3136/4
#define NG 16                // channel groups in phase 1
#define CPG 16               // channels per group
#define GRID 1024            // 4 blocks/CU * 256 CU (co-resident)
#define BLK 256

__device__ __forceinline__ float4 f4max(float4 a, float4 b) {
    float4 r;
    r.x = fmaxf(a.x, b.x); r.y = fmaxf(a.y, b.y);
    r.z = fmaxf(a.z, b.z); r.w = fmaxf(a.w, b.w);
    return r;
}
__device__ __forceinline__ float4 f4add(float4 a, float4 b) {
    float4 r;
    r.x = a.x + b.x; r.y = a.y + b.y; r.z = a.z + b.z; r.w = a.w + b.w;
    return r;
}

// ---------------- fused cooperative kernel ----------------
__global__ __launch_bounds__(BLK, 4) void k_fused(
        const float* __restrict__ x, const float* __restrict__ cw,
        const float* __restrict__ gamma, const float* __restrict__ beta,
        float* __restrict__ out, float* __restrict__ pmax,
        float* __restrict__ psum, float* __restrict__ pool,
        float* __restrict__ conv, float* __restrict__ stats) {
    cg::grid_group grid = cg::this_grid();
    const int tid = threadIdx.x;
    const int bid = blockIdx.x;

    if (bid == 0 && tid == 0) { stats[0] = 0.f; stats[1] = 0.f; }

    __shared__ float w[64];
    if (tid < 50) w[tid] = cw[tid];
    __syncthreads();

    // ---- phase 1: per-group channel max/sum partials (reads all of x) ----
    // row = (tile of 64 quads, channel group g). 392*16 = 6272 rows over
    // 1024 blocks * 4 rows/block = 4096 slots, grid-stride.
    const int tx = tid & 63;
    const int ty = tid >> 6;          // 0..3
    const int NROWS = 392 * NG;
    for (int row = bid * 4 + ty; row < NROWS; row += GRID * 4) {
        const int tile = row >> 4;
        const int g = row & (NG - 1);
        const int qid = tile * 64 + tx;          // 0..NQ-1
        const int n = qid / QPP;
        const int hwq = qid - n * QPP;
        const float4* p = (const float4*)x + (size_t)(n * CC + g * CPG) * QPP + hwq;
        float4 v = p[0];
        float4 vmax = v, vsum = v;
#pragma unroll
        for (int i = 1; i < CPG; ++i) {
            float4 t = p[(size_t)i * QPP];
            vmax = f4max(vmax, t);
            vsum = f4add(vsum, t);
        }
        ((float4*)pmax)[(size_t)g * NQ + qid] = vmax;
        ((float4*)psum)[(size_t)g * NQ + qid] = vsum;
    }
    grid.sync();

    // ---- phase 2a: reduce NG partials -> pool [N,2,HW] ----
    for (int q = bid * BLK + tid; q < NQ; q += GRID * BLK) {
        float4 m = ((const float4*)pmax)[q];
        float4 s = ((const float4*)psum)[q];
#pragma unroll
        for (int g = 1; g < NG; ++g) {
            m = f4max(m, ((const float4*)pmax)[(size_t)g * NQ + q]);
            s = f4add(s, ((const float4*)psum)[(size_t)g * NQ + q]);
        }
        const int n = q / QPP;
        const int hwq = q - n * QPP;
        ((float4*)pool)[(size_t)n * 2 * QPP + hwq] = m;
        float4 mean;
        mean.x = s.x * (1.f / 256.f); mean.y = s.y * (1.f / 256.f);
        mean.z = s.z * (1.f / 256.f); mean.w = s.w * (1.f / 256.f);
        ((float4*)pool)[(size_t)n * 2 * QPP + QPP + hwq] = mean;
    }
    grid.sync();

    // ---- phase 2b: 5x5 conv (2->1 ch, SAME) + BN stat partials ----
    {
        const int gid = bid * BLK + tid;
        float s = 0.f, s2 = 0.f;
        if (gid < NHW) {
            const int n = gid / HWSZ;
            const int hw = gid - n * HWSZ;
            const int h = hw / WW;
            const int wc = hw - h * WW;
            const float* pb = pool + (size_t)n * 2 * HWSZ;
            float acc = 0.f;
#pragma unroll
            for (int ci = 0; ci < 2; ++ci)
#pragma unroll
                for (int kh = 0; kh < 5; ++kh) {
                    const int hh = h + kh - 2;
                    if (hh < 0 || hh >= HH) continue;
#pragma unroll
                    for (int kw = 0; kw < 5; ++kw) {
                        const int wwc = wc + kw - 2;
                        if (wwc < 0 || wwc >= WW) continue;
                        acc += pb[ci * HWSZ + hh * WW + wwc] * w[ci * 25 + kh * 5 + kw];
                    }
                }
            conv[gid] = acc;
            s = acc;
            s2 = acc * acc;
        }
#pragma unroll
        for (int i = 1; i < 64; i <<= 1) {
            s += __shfl_xor(s, i);
            s2 += __shfl_xor(s2, i);
        }
        if ((tid & 63) == 0 && s2 != 0.f) {
            atomicAdd(&stats[0], s);
            atomicAdd(&stats[1], s2);
        }
    }
    grid.sync();

    // ---- phase 3: finalize BN, gate = sigmoid(sigmoid(bn)), apply ----
    {
        const float invM = 1.f / (float)NHW;
        const float mean = stats[0] * invM;
        const float var = stats[1] * invM - mean * mean;
        const float scale = rsqrtf(var + 1e-5f) * gamma[0];
        const float shift = beta[0] - mean * scale;

        const float4* x4 = (const float4*)x;
        const float4* c4 = (const float4*)conv;
        float4* o4 = (float4*)out;
        for (int q = bid * BLK + tid; q < TOT4; q += GRID * BLK) {
            const int plane = q / QPP;
            const int hwq = q - plane * QPP;
            const int n = plane >> 8;
            float4 cv = c4[n * QPP + hwq];
            float4 xv = x4[q];
            float4 r;
            {
                float v = cv.x * scale + shift;
                float s1 = 1.f / (1.f + __expf(-v));
                r.x = xv.x * (1.f / (1.f + __expf(-s1)));
            }
            {
                float v = cv.y * scale + shift;
                float s1 = 1.f / (1.f + __expf(-v));
                r.y = xv.y * (1.f / (1.f + __expf(-s1)));
            }
            {
                float v = cv.z * scale + shift;
                float s1 = 1.f / (1.f + __expf(-v));
                r.z = xv.z * (1.f / (1.f + __expf(-s1)));
            }
            {
                float v = cv.w * scale + shift;
                float s1 = 1.f / (1.f + __expf(-v));
                r.w = xv.w * (1.f / (1.f + __expf(-s1)));
            }
            o4[q] = r;
        }
    }
}

// ---------------- fallback path (round-2 kernels) ----------------
__global__ __launch_bounds__(512) void k_pool(const float* __restrict__ x,
                                              float* __restrict__ pool,
                                              float* __restrict__ stats) {
    if (blockIdx.x == 0 && threadIdx.x == 0 && threadIdx.y == 0) {
        stats[0] = 0.f;
        stats[1] = 0.f;
    }
    const int tx = threadIdx.x;
    const int ty = threadIdx.y;
    const int qid = blockIdx.x * 64 + tx;
    const int n = qid / QPP;
    const int hwq = qid - n * QPP;

    const float4* p = (const float4*)x + (size_t)(n * CC + ty * 32) * QPP + hwq;
    float4 v0 = p[0];
    float4 vmax = v0, vsum = v0;
#pragma unroll 8
    for (int i = 1; i < 32; ++i) {
        float4 v = p[(size_t)i * QPP];
        vmax = f4max(vmax, v);
        vsum = f4add(vsum, v);
    }
    __shared__ float4 smax[8][64];
    __shared__ float4 ssum[8][64];
    smax[ty][tx] = vmax;
    ssum[ty][tx] = vsum;
    __syncthreads();
    if (ty == 0) {
        float4 m = smax[0][tx];
        float4 s = ssum[0][tx];
#pragma unroll
        for (int g = 1; g < 8; ++g) {
            m = f4max(m, smax[g][tx]);
            s = f4add(s, ssum[g][tx]);
        }
        float4* pm = (float4*)pool + (size_t)n * 2 * QPP + hwq;
        pm[0] = m;
        float4 mean;
        mean.x = s.x * (1.f / 256.f); mean.y = s.y * (1.f / 256.f);
        mean.z = s.z * (1.f / 256.f); mean.w = s.w * (1.f / 256.f);
        pm[QPP] = mean;
    }
}

__global__ __launch_bounds__(256) void k_conv(const float* __restrict__ pool,
                                              const float* __restrict__ cw,
                                              float* __restrict__ conv,
                                              float* __restrict__ stats) {
    __shared__ float w[50];
    const int tid = threadIdx.x;
    if (tid < 50) w[tid] = cw[tid];
    __syncthreads();

    const int gid = blockIdx.x * 256 + tid;
    const int n = gid / HWSZ;
    const int hw = gid - n * HWSZ;
    const int h = hw / WW;
    const int wc = hw - h * WW;

    const float* pb = pool + (size_t)n * 2 * HWSZ;
    float acc = 0.f;
#pragma unroll
    for (int ci = 0; ci < 2; ++ci)
#pragma unroll
        for (int kh = 0; kh < 5; ++kh) {
            const int hh = h + kh - 2;
            if (hh < 0 || hh >= HH) continue;
#pragma unroll
            for (int kw = 0; kw < 5; ++kw) {
                const int wwc = wc + kw - 2;
                if (wwc < 0 || wwc >= WW) continue;
                acc += pb[ci * HWSZ + hh * WW + wwc] * w[ci * 25 + kh * 5 + kw];
            }
        }
    conv[gid] = acc;

    float s = acc, s2 = acc * acc;
#pragma unroll
    for (int i = 1; i < 64; i <<= 1) {
        s += __shfl_xor(s, i);
        s2 += __shfl_xor(s2, i);
    }
    if ((tid & 63) == 0) {
        atomicAdd(&stats[0], s);
        atomicAdd(&stats[1], s2);
    }
}

__global__ __launch_bounds__(256) void k_apply(const float* __restrict__ x,
                                               const float* __restrict__ conv,
                                               const float* __restrict__ stats,
                                               const float* __restrict__ gamma,
                                               const float* __restrict__ beta,
                                               float* __restrict__ out) {
    const float invM = 1.f / (float)NHW;
    const float mean = stats[0] * invM;
    const float var = stats[1] * invM - mean * mean;
    const float scale = rsqrtf(var + 1e-5f) * gamma[0];
    const float shift = beta[0] - mean * scale;

    const float4* x4 = (const float4*)x;
    const float4* c4 = (const float4*)conv;
    float4* o4 = (float4*)out;
    for (int q = blockIdx.x * blockDim.x + threadIdx.x; q < TOT4;
         q += gridDim.x * blockDim.x) {
        const int plane = q / QPP;
        const int hwq = q - plane * QPP;
        const int n = plane >> 8;
        float4 cv = c4[n * QPP + hwq];
        float4 xv = x4[q];
        float4 r;
        {
            float v = cv.x * scale + shift;
            float s1 = 1.f / (1.f + __expf(-v));
            r.x = xv.x * (1.f / (1.f + __expf(-s1)));
        }
        {
            float v = cv.y * scale + shift;
            float s1 = 1.f / (1.f + __expf(-v));
            r.y = xv.y * (1.f / (1.f + __expf(-s1)));
        }
        {
            float v = cv.z * scale + shift;
            float s1 = 1.f / (1.f + __expf(-v));
            r.z = xv.z * (1.f / (1.f + __expf(-s1)));
        }
        {
            float v = cv.w * scale + shift;
            float s1 = 1.f / (1.f + __expf(-v));
            r.w = xv.w * (1.f / (1.f + __expf(-s1)));
        }
        o4[q] = r;
    }
}

extern "C" void kernel_launch(void* const* d_in, const int* in_sizes, int n_in,
                              void* d_out, int out_size, void* d_ws, size_t ws_size,
                              hipStream_t stream) {
    const float* x = (const float*)d_in[0];
    const float* cw = (const float*)d_in[1];
    const float* gamma = (const float*)d_in[2];
    const float* beta = (const float*)d_in[3];
    float* out = (float*)d_out;

    float* ws = (float*)d_ws;
    float* pmax = ws;                        // NG*NQ float4 = 1605632 floats
    float* psum = pmax + (size_t)NG * NQ * 4;
    float* pool = psum + (size_t)NG * NQ * 4; // 2*NHW floats
    float* conv = pool + 2 * NHW;             // NHW floats
    float* stats = conv + NHW;                // 2 floats

    void* args[] = {(void*)&x, (void*)&cw, (void*)&gamma, (void*)&beta,
                    (void*)&out, (void*)&pmax, (void*)&psum, (void*)&pool,
                    (void*)&conv, (void*)&stats};
    hipError_t err = hipLaunchCooperativeKernel((void*)k_fused, dim3(GRID),
                                                dim3(BLK), args, 0, stream);
    if (err != hipSuccess) {
        // deterministic fallback: 3-kernel path
        k_pool<<<392, dim3(64, 8), 0, stream>>>(x, pool, stats);
        k_conv<<<392, 256, 0, stream>>>(pool, cw, conv, stats);
        k_apply<<<4096, 256, 0, stream>>>(x, conv, stats, gamma, beta, out);
    }
}

// Round 5
// 97.782 us; speedup vs baseline: 4.2069x; 4.2069x over previous
//
#include <hip/hip_runtime.h>

#define NN 32
#define CC 256
#define HH 56
#define WW 56
#define HWSZ 3136            // 56*56
#define QPP 784              // float4 quads per spatial plane (3136/4)
#define NQ 25088             // quads over N*HW = 32*784
#define NHW 100352           // 32*3136
#define CBLKS 32             // channel chunks in k_apply (8 ch each)
#define APPLY_THREADS (NQ * CBLKS)   // 802816

typedef float v4f __attribute__((ext_vector_type(4)));

__device__ __forceinline__ float4 f4max(float4 a, float4 b) {
    float4 r;
    r.x = fmaxf(a.x, b.x); r.y = fmaxf(a.y, b.y);
    r.z = fmaxf(a.z, b.z); r.w = fmaxf(a.w, b.w);
    return r;
}
__device__ __forceinline__ float4 f4add(float4 a, float4 b) {
    float4 r;
    r.x = a.x + b.x; r.y = a.y + b.y; r.z = a.z + b.z; r.w = a.w + b.w;
    return r;
}

// ---------------- K1: channel max + mean pool ----------------
// grid: 392 blocks, block (64,8). Block covers 64 float4-quads (256 hw
// positions); ty splits 256 channels into 8 groups of 32.
__global__ __launch_bounds__(512) void k_pool(const float* __restrict__ x,
                                              float* __restrict__ pool,
                                              float* __restrict__ stats) {
    if (blockIdx.x == 0 && threadIdx.x == 0 && threadIdx.y == 0) {
        stats[0] = 0.f;
        stats[1] = 0.f;
    }
    const int tx = threadIdx.x;              // 0..63 quad-in-tile
    const int ty = threadIdx.y;              // 0..7 channel group (32 ch)
    const int qid = blockIdx.x * 64 + tx;    // global quad over N*HW
    const int n = qid / QPP;
    const int hwq = qid - n * QPP;

    const float4* p = (const float4*)x + (size_t)(n * CC + ty * 32) * QPP + hwq;
    float4 v0 = p[0];
    float4 vmax = v0, vsum = v0;
#pragma unroll 8
    for (int i = 1; i < 32; ++i) {
        float4 v = p[(size_t)i * QPP];
        vmax = f4max(vmax, v);
        vsum = f4add(vsum, v);
    }
    __shared__ float4 smax[8][64];
    __shared__ float4 ssum[8][64];
    smax[ty][tx] = vmax;
    ssum[ty][tx] = vsum;
    __syncthreads();
    if (ty == 0) {
        float4 m = smax[0][tx];
        float4 s = ssum[0][tx];
#pragma unroll
        for (int g = 1; g < 8; ++g) {
            m = f4max(m, smax[g][tx]);
            s = f4add(s, ssum[g][tx]);
        }
        float4* pm = (float4*)pool + (size_t)n * 2 * QPP + hwq;
        pm[0] = m;                       // channel 0: max
        float4 mean;
        mean.x = s.x * 0.00390625f; mean.y = s.y * 0.00390625f;
        mean.z = s.z * 0.00390625f; mean.w = s.w * 0.00390625f;
        pm[QPP] = mean;                  // channel 1: mean
    }
}

// ---------------- K2: 5x5 conv (2->1 ch, SAME) + BN stat partials ----------
__global__ __launch_bounds__(256) void k_conv(const float* __restrict__ pool,
                                              const float* __restrict__ cw,
                                              float* __restrict__ conv,
                                              float* __restrict__ stats) {
    __shared__ float w[50];
    const int tid = threadIdx.x;
    if (tid < 50) w[tid] = cw[tid];
    __syncthreads();

    const int gid = blockIdx.x * 256 + tid;   // 0..NHW-1
    const int n = gid / HWSZ;
    const int hw = gid - n * HWSZ;
    const int h = hw / WW;
    const int wc = hw - h * WW;

    const float* pb = pool + (size_t)n * 2 * HWSZ;
    float acc = 0.f;
#pragma unroll
    for (int ci = 0; ci < 2; ++ci)
#pragma unroll
        for (int kh = 0; kh < 5; ++kh) {
            const int hh = h + kh - 2;
            if (hh < 0 || hh >= HH) continue;
#pragma unroll
            for (int kw = 0; kw < 5; ++kw) {
                const int wwc = wc + kw - 2;
                if (wwc < 0 || wwc >= WW) continue;
                acc += pb[ci * HWSZ + hh * WW + wwc] * w[ci * 25 + kh * 5 + kw];
            }
        }
    conv[gid] = acc;

    float s = acc, s2 = acc * acc;
#pragma unroll
    for (int i = 1; i < 64; i <<= 1) {
        s += __shfl_xor(s, i);
        s2 += __shfl_xor(s2, i);
    }
    if ((tid & 63) == 0) {
        atomicAdd(&stats[0], s);
        atomicAdd(&stats[1], s2);
    }
}

// ---------------- K3: fused BN + double-sigmoid gate + apply ---------------
// One thread per (n, hw-quad, 8-channel chunk). Gate computed ONCE per
// thread (16 transcendentals), then 8 plane-strided load-mul-store iters.
__global__ __launch_bounds__(256) void k_apply(const float* __restrict__ x,
                                               const float* __restrict__ conv,
                                               const float* __restrict__ stats,
                                               const float* __restrict__ gamma,
                                               const float* __restrict__ beta,
                                               float* __restrict__ out) {
    const float invM = 1.f / (float)NHW;
    const float mean = stats[0] * invM;
    const float var = stats[1] * invM - mean * mean;
    const float scale = rsqrtf(var + 1e-5f) * gamma[0];
    const float shift = beta[0] - mean * scale;

    const int gid = blockIdx.x * 256 + threadIdx.x;   // 0..APPLY_THREADS-1
    const int v = gid / QPP;          // n*CBLKS + cblk
    const int hwq = gid - v * QPP;
    const int cblk = v & (CBLKS - 1);
    const int n = v >> 5;

    // gate for this (n, hw-quad), computed once
    const float4 cv = ((const float4*)conv)[n * QPP + hwq];
    float4 g;
    {
        float t = cv.x * scale + shift;
        float s1 = 1.f / (1.f + __expf(-t));
        g.x = 1.f / (1.f + __expf(-s1));
    }
    {
        float t = cv.y * scale + shift;
        float s1 = 1.f / (1.f + __expf(-t));
        g.y = 1.f / (1.f + __expf(-s1));
    }
    {
        float t = cv.z * scale + shift;
        float s1 = 1.f / (1.f + __expf(-t));
        g.z = 1.f / (1.f + __expf(-s1));
    }
    {
        float t = cv.w * scale + shift;
        float s1 = 1.f / (1.f + __expf(-t));
        g.w = 1.f / (1.f + __expf(-s1));
    }

    const float4* x4 = (const float4*)x + (size_t)(n * CC + cblk * 8) * QPP + hwq;
    v4f* o4 = (v4f*)out + (size_t)(n * CC + cblk * 8) * QPP + hwq;
#pragma unroll
    for (int i = 0; i < 8; ++i) {
        float4 xv = x4[(size_t)i * QPP];
        v4f r;
        r.x = xv.x * g.x; r.y = xv.y * g.y;
        r.z = xv.z * g.z; r.w = xv.w * g.w;
        __builtin_nontemporal_store(r, &o4[(size_t)i * QPP]);
    }
}

extern "C" void kernel_launch(void* const* d_in, const int* in_sizes, int n_in,
                              void* d_out, int out_size, void* d_ws, size_t ws_size,
                              hipStream_t stream) {
    const float* x = (const float*)d_in[0];
    const float* cw = (const float*)d_in[1];
    const float* gamma = (const float*)d_in[2];
    const float* beta = (const float*)d_in[3];
    float* out = (float*)d_out;

    float* ws = (float*)d_ws;
    float* pool = ws;                 // 2*NHW floats
    float* conv = ws + 2 * NHW;       // NHW floats
    float* stats = ws + 3 * NHW;      // 2 floats

    k_pool<<<392, dim3(64, 8), 0, stream>>>(x, pool, stats);
    k_conv<<<392, 256, 0, stream>>>(pool, cw, conv, stats);
    k_apply<<<APPLY_THREADS / 256, 256, 0, stream>>>(x, conv, stats, gamma,
                                                     beta, out);
}